// Round 4
// baseline (1267.549 us; speedup 1.0000x reference)
//
#include <hip/hip_runtime.h>

#define DFEAT 64
#define NG 64
#define TILE 128        // nodes per bucket/tile (aligned: bucket = tgt >> 7)

// ---------------- bucket histogram: gcount[b] += #edges with tgt>>7 == b ----------
__global__ __launch_bounds__(256) void k_hist(const int* __restrict__ col,
                                              int* __restrict__ gcount,
                                              int e, int nb, int nblk) {
  extern __shared__ int hist[];  // nb ints
  int tid = threadIdx.x;
  for (int b = tid; b < nb; b += 256) hist[b] = 0;
  __syncthreads();
  for (int i = blockIdx.x * 256 + tid; i < e; i += nblk * 256)
    atomicAdd(&hist[col[i] >> 7], 1);
  __syncthreads();
  for (int b = tid; b < nb; b += 256)
    if (hist[b]) atomicAdd(&gcount[b], hist[b]);
}

// ---------------- scan buckets -> base[0..nb], cursor = base --------------------
__global__ __launch_bounds__(1024) void k_bscan(const int* __restrict__ gcount,
                                                int* __restrict__ base,
                                                int* __restrict__ cursor, int nb) {
  __shared__ int sh[1024];
  int tid = threadIdx.x;
  int v = (tid < nb) ? gcount[tid] : 0;
  sh[tid] = v;
  __syncthreads();
  for (int off = 1; off < 1024; off <<= 1) {
    int t = (tid >= off) ? sh[tid - off] : 0;
    __syncthreads();
    sh[tid] += t;
    __syncthreads();
  }
  if (tid < nb) {
    int ex = sh[tid] - v;
    base[tid] = ex;
    cursor[tid] = ex;
  }
  if (tid == 0) base[nb] = sh[1023];
}

// ---------------- bin edges: pairs[pos] = (src,tgt), grouped by tile ------------
__global__ __launch_bounds__(256) void k_bin(const int* __restrict__ row,
                                             const int* __restrict__ col,
                                             int* __restrict__ cursor,
                                             int2* __restrict__ pairs, int e) {
  int i = blockIdx.x * 256 + threadIdx.x;
  if (i < e) {
    int s = row[i], t = col[i];
    int pos = atomicAdd(&cursor[t >> 7], 1);
    pairs[pos] = make_int2(s, t);
  }
}

// ---------------- per-node degree via bucket-local LDS counts -> dinv -----------
__global__ __launch_bounds__(256) void k_dinv(const int2* __restrict__ pairs,
                                              const int* __restrict__ base,
                                              float* __restrict__ dinv, int n) {
  __shared__ int cnt[TILE];
  int tid = threadIdx.x;
  int b = blockIdx.x;
  if (tid < TILE) cnt[tid] = 0;
  __syncthreads();
  int e0 = base[b], e1 = base[b + 1];
  for (int i = e0 + tid; i < e1; i += 256)
    atomicAdd(&cnt[pairs[i].y & (TILE - 1)], 1);
  __syncthreads();
  int node = b * TILE + tid;
  if (tid < TILE && node < n) dinv[node] = rsqrtf(1.0f + (float)cnt[tid]);
}

// ---------------- GEMM: out[n,64] = in[n,64] @ W[64,64] ----------------
#define IST 68
__global__ __launch_bounds__(256) void k_gemm(const float* __restrict__ in,
                                              const float* __restrict__ W,
                                              float* __restrict__ out, int n) {
  __shared__ float Ws[64 * 64];
  __shared__ float IsT[64 * IST];
  int tid = threadIdx.x;
  int row0 = blockIdx.x * 64;
  for (int j = tid; j < 4096; j += 256) Ws[j] = W[j];
  for (int s = 0; s < 4; ++s) {
    int g = tid * 4 + s * 1024;
    int r = g >> 6;
    int kb = g & 63;
    float4 v = make_float4(0.f, 0.f, 0.f, 0.f);
    if (row0 + r < n) v = *(const float4*)(&in[(size_t)(row0 + r) * 64 + kb]);
    IsT[(kb + 0) * IST + r] = v.x;
    IsT[(kb + 1) * IST + r] = v.y;
    IsT[(kb + 2) * IST + r] = v.z;
    IsT[(kb + 3) * IST + r] = v.w;
  }
  __syncthreads();
  int dgrp = tid & 15;
  int rq = tid >> 4;
  float4 acc0 = {0.f, 0.f, 0.f, 0.f}, acc1 = acc0, acc2 = acc0, acc3 = acc0;
  for (int k = 0; k < 64; ++k) {
    float4 wv = *(const float4*)(&Ws[k * 64 + dgrp * 4]);
    float4 iv = *(const float4*)(&IsT[k * IST + rq * 4]);
    acc0.x += iv.x * wv.x; acc0.y += iv.x * wv.y; acc0.z += iv.x * wv.z; acc0.w += iv.x * wv.w;
    acc1.x += iv.y * wv.x; acc1.y += iv.y * wv.y; acc1.z += iv.y * wv.z; acc1.w += iv.y * wv.w;
    acc2.x += iv.z * wv.x; acc2.y += iv.z * wv.y; acc2.z += iv.z * wv.z; acc2.w += iv.z * wv.w;
    acc3.x += iv.w * wv.x; acc3.y += iv.w * wv.y; acc3.z += iv.w * wv.z; acc3.w += iv.w * wv.w;
  }
  int rbase = row0 + rq * 4;
  if (rbase + 0 < n) *(float4*)(&out[(size_t)(rbase + 0) * 64 + dgrp * 4]) = acc0;
  if (rbase + 1 < n) *(float4*)(&out[(size_t)(rbase + 1) * 64 + dgrp * 4]) = acc1;
  if (rbase + 2 < n) *(float4*)(&out[(size_t)(rbase + 2) * 64 + dgrp * 4]) = acc2;
  if (rbase + 3 < n) *(float4*)(&out[(size_t)(rbase + 3) * 64 + dgrp * 4]) = acc3;
}

// ---------------- tile gather: block per 128-node tile, LDS accumulate ----------
__global__ __launch_bounds__(256) void k_tile(const int2* __restrict__ pairs,
                                              const int* __restrict__ base,
                                              const float* __restrict__ dinv,
                                              const float* __restrict__ h,
                                              const float* __restrict__ bias,
                                              float* __restrict__ o, int n) {
  __shared__ float acc[TILE * 64];   // 32 KB
  __shared__ float dtl[TILE];
  int tid = threadIdx.x;
  int b = blockIdx.x;
  int tile0 = b * TILE;
  int tn = min(TILE, n - tile0);
  int lane = tid & 63;
  if (tid < TILE) dtl[tid] = (tid < tn) ? dinv[tile0 + tid] : 0.f;
  for (int idx = tid; idx < tn * 64; idx += 256) {
    int node = idx >> 6;
    float d = dinv[tile0 + node];
    acc[idx] = bias[idx & 63] + d * d * h[(size_t)(tile0 + node) * 64 + (idx & 63)];
  }
  __syncthreads();
  int e0 = base[b], e1 = base[b + 1];
  int w = tid >> 6;
  int ei = e0 + w;
  for (; ei + 12 < e1; ei += 16) {
    int2 p0 = pairs[ei];
    int2 p1 = pairs[ei + 4];
    int2 p2 = pairs[ei + 8];
    int2 p3 = pairs[ei + 12];
    float v0 = h[(size_t)p0.x * 64 + lane];
    float v1 = h[(size_t)p1.x * 64 + lane];
    float v2 = h[(size_t)p2.x * 64 + lane];
    float v3 = h[(size_t)p3.x * 64 + lane];
    float w0 = dinv[p0.x] * dtl[p0.y & (TILE - 1)];
    float w1 = dinv[p1.x] * dtl[p1.y & (TILE - 1)];
    float w2 = dinv[p2.x] * dtl[p2.y & (TILE - 1)];
    float w3 = dinv[p3.x] * dtl[p3.y & (TILE - 1)];
    atomicAdd(&acc[(p0.y & (TILE - 1)) * 64 + lane], w0 * v0);
    atomicAdd(&acc[(p1.y & (TILE - 1)) * 64 + lane], w1 * v1);
    atomicAdd(&acc[(p2.y & (TILE - 1)) * 64 + lane], w2 * v2);
    atomicAdd(&acc[(p3.y & (TILE - 1)) * 64 + lane], w3 * v3);
  }
  for (; ei < e1; ei += 4) {
    int2 p = pairs[ei];
    float v = h[(size_t)p.x * 64 + lane];
    float wt = dinv[p.x] * dtl[p.y & (TILE - 1)];
    atomicAdd(&acc[(p.y & (TILE - 1)) * 64 + lane], wt * v);
  }
  __syncthreads();
  for (int idx = tid; idx < tn * 64; idx += 256)
    o[(size_t)tile0 * 64 + idx] = acc[idx];
}

// ---------------- pooling: batch sorted; 1 wave per 64-node chunk ----------------
__global__ void k_pool(const float* __restrict__ o, const int* __restrict__ batch,
                       float* __restrict__ sums, float* __restrict__ cntf, int n) {
  int d = threadIdx.x;
  int start = blockIdx.x * 64;
  if (start >= n) return;
  int end = min(start + 64, n);
  int curg = batch[start];
  float acc = 0.f, cnt = 0.f;
  for (int i = start; i < end; ++i) {
    int g = batch[i];
    if (g != curg) {
      unsafeAtomicAdd(&sums[curg * 64 + d], acc);
      if (d == 0) unsafeAtomicAdd(&cntf[curg], cnt);
      acc = 0.f;
      cnt = 0.f;
      curg = g;
    }
    acc += o[(size_t)i * 64 + d];
    cnt += 1.f;
  }
  unsafeAtomicAdd(&sums[curg * 64 + d], acc);
  if (d == 0) unsafeAtomicAdd(&cntf[curg], cnt);
}

// ---------------- final ----------------
__global__ void k_final(const float* __restrict__ sums, const float* __restrict__ cntf,
                        float* __restrict__ out) {
  int i = blockIdx.x * 256 + threadIdx.x;
  if (i < NG * DFEAT) out[i] = sums[i] / fmaxf(cntf[i >> 6], 1.0f);
}

extern "C" void kernel_launch(void* const* d_in, const int* in_sizes, int n_in,
                              void* d_out, int out_size, void* d_ws, size_t ws_size,
                              hipStream_t stream) {
  const float* x = (const float*)d_in[0];
  const int* ei = (const int*)d_in[1];
  const int* bat = (const int*)d_in[2];
  const float* W1 = (const float*)d_in[3];
  const float* b1 = (const float*)d_in[4];
  const float* W2 = (const float*)d_in[5];
  const float* b2 = (const float*)d_in[6];
  float* out = (float*)d_out;

  int n = in_sizes[0] / 64;  // 100000
  int e = in_sizes[1] / 2;   // 1000000
  const int* rowp = ei;      // sources
  const int* colp = ei + e;  // targets
  int nb = (n + TILE - 1) / TILE;  // 782 buckets

  // workspace layout: [gcount nb][sums 4096][cntf 64] (zeroed together) | rest
  char* ws = (char*)d_ws;
  size_t off = 0;
  auto alloc = [&](size_t elems) {
    void* p = ws + off;
    off += ((elems * 4 + 255) & ~(size_t)255);
    return p;
  };
  int* gcount = (int*)alloc(nb);
  float* sums = (float*)alloc(NG * DFEAT);
  float* cntf = (float*)alloc(NG);
  size_t zbytes = off;  // zero everything up to here in one memset
  int* base = (int*)alloc(nb + 1);
  int* cursor = (int*)alloc(nb);
  float* dinv = (float*)alloc(n);
  int2* pairs = (int2*)alloc((size_t)e * 2);
  float* bufA = (float*)alloc((size_t)n * 64);
  float* bufB = (float*)alloc((size_t)n * 64);

  int nbe = (e + 255) / 256;
  int nbg = (n + 63) / 64;

  hipMemsetAsync(gcount, 0, zbytes, stream);
  k_hist<<<256, 256, nb * sizeof(int), stream>>>(colp, gcount, e, nb, 256);
  k_bscan<<<1, 1024, 0, stream>>>(gcount, base, cursor, nb);
  k_bin<<<nbe, 256, 0, stream>>>(rowp, colp, cursor, pairs, e);
  k_dinv<<<nb, 256, 0, stream>>>(pairs, base, dinv, n);

  // layer 1: gemm(x,W1) -> bufA ; propagate(bufA) -> bufB
  k_gemm<<<nbg, 256, 0, stream>>>(x, W1, bufA, n);
  k_tile<<<nb, 256, 0, stream>>>(pairs, base, dinv, bufA, b1, bufB, n);

  // layer 2: gemm(bufB,W2) -> bufA ; propagate(bufA) -> bufB   [FIXED operand order]
  k_gemm<<<nbg, 256, 0, stream>>>(bufB, W2, bufA, n);
  k_tile<<<nb, 256, 0, stream>>>(pairs, base, dinv, bufA, b2, bufB, n);

  // pool on bufB (layer-2 propagated output)
  k_pool<<<(n + 63) / 64, 64, 0, stream>>>(bufB, bat, sums, cntf, n);
  k_final<<<(NG * DFEAT + 255) / 256, 256, 0, stream>>>(sums, cntf, out);
}

// Round 5
// 491.570 us; speedup vs baseline: 2.5786x; 2.5786x over previous
//
#include <hip/hip_runtime.h>

#define DFEAT 64
#define NG 64
#define TILE 128        // nodes per bucket/tile (bucket = tgt >> 7)

// ---------------- bucket histogram: gcount[b] += #edges with tgt>>7 == b --------
__global__ __launch_bounds__(256) void k_hist(const int* __restrict__ col,
                                              int* __restrict__ gcount,
                                              int e, int nb, int nblk) {
  extern __shared__ int hist[];  // nb ints
  int tid = threadIdx.x;
  for (int b = tid; b < nb; b += 256) hist[b] = 0;
  __syncthreads();
  for (int i = blockIdx.x * 256 + tid; i < e; i += nblk * 256)
    atomicAdd(&hist[col[i] >> 7], 1);
  __syncthreads();
  for (int b = tid; b < nb; b += 256)
    if (hist[b]) atomicAdd(&gcount[b], hist[b]);
}

// ---------------- scan buckets -> base[0..nb], cursor = base --------------------
__global__ __launch_bounds__(1024) void k_bscan(const int* __restrict__ gcount,
                                                int* __restrict__ base,
                                                int* __restrict__ cursor, int nb) {
  __shared__ int sh[1024];
  int tid = threadIdx.x;
  int v = (tid < nb) ? gcount[tid] : 0;
  sh[tid] = v;
  __syncthreads();
  for (int off = 1; off < 1024; off <<= 1) {
    int t = (tid >= off) ? sh[tid - off] : 0;
    __syncthreads();
    sh[tid] += t;
    __syncthreads();
  }
  if (tid < nb) {
    int ex = sh[tid] - v;
    base[tid] = ex;
    cursor[tid] = ex;
  }
  if (tid == 0) base[nb] = sh[1023];
}

// ---------------- bin edges: pairs[pos] = (src,tgt), grouped by tile ------------
__global__ __launch_bounds__(256) void k_bin(const int* __restrict__ row,
                                             const int* __restrict__ col,
                                             int* __restrict__ cursor,
                                             int2* __restrict__ pairs, int e) {
  int i = blockIdx.x * 256 + threadIdx.x;
  if (i < e) {
    int s = row[i], t = col[i];
    int pos = atomicAdd(&cursor[t >> 7], 1);
    pairs[pos] = make_int2(s, t);
  }
}

// ---------------- per-tile CSR: node-ordered srcs, starts[], dinv ----------------
__global__ __launch_bounds__(256) void k_csr(const int2* __restrict__ pairs,
                                             const int* __restrict__ base,
                                             int* __restrict__ starts,
                                             int* __restrict__ srcs,
                                             float* __restrict__ dinv,
                                             int n, int e) {
  __shared__ int cnt[TILE];
  __shared__ int cur[TILE];
  __shared__ int sc[TILE];
  int tid = threadIdx.x;
  int b = blockIdx.x;
  int tile0 = b * TILE;
  if (tid < TILE) cnt[tid] = 0;
  __syncthreads();
  int e0 = base[b], e1 = base[b + 1];
  for (int i = e0 + tid; i < e1; i += 256)
    atomicAdd(&cnt[pairs[i].y & (TILE - 1)], 1);
  __syncthreads();
  int c = (tid < TILE) ? cnt[tid] : 0;
  if (tid < TILE) sc[tid] = c;
  __syncthreads();
  for (int off = 1; off < TILE; off <<= 1) {
    int t = (tid < TILE && tid >= off) ? sc[tid - off] : 0;
    __syncthreads();
    if (tid < TILE) sc[tid] += t;
    __syncthreads();
  }
  if (tid < TILE) {
    int excl = sc[tid] - c;
    cur[tid] = excl;
    int node = tile0 + tid;
    if (node < n) {
      starts[node] = e0 + excl;
      dinv[node] = rsqrtf(1.0f + (float)c);
    }
  }
  if (b == 0 && tid == 0) starts[n] = e;
  __syncthreads();
  for (int i = e0 + tid; i < e1; i += 256) {
    int2 p = pairs[i];
    int pos = atomicAdd(&cur[p.y & (TILE - 1)], 1);
    srcs[e0 + pos] = p.x;
  }
}

// ---------------- GEMM: out[n,64] = in[n,64] @ W[64,64] ----------------
#define IST 68
__global__ __launch_bounds__(256) void k_gemm(const float* __restrict__ in,
                                              const float* __restrict__ W,
                                              float* __restrict__ out, int n) {
  __shared__ float Ws[64 * 64];
  __shared__ float IsT[64 * IST];
  int tid = threadIdx.x;
  int row0 = blockIdx.x * 64;
  for (int j = tid; j < 4096; j += 256) Ws[j] = W[j];
  for (int s = 0; s < 4; ++s) {
    int g = tid * 4 + s * 1024;
    int r = g >> 6;
    int kb = g & 63;
    float4 v = make_float4(0.f, 0.f, 0.f, 0.f);
    if (row0 + r < n) v = *(const float4*)(&in[(size_t)(row0 + r) * 64 + kb]);
    IsT[(kb + 0) * IST + r] = v.x;
    IsT[(kb + 1) * IST + r] = v.y;
    IsT[(kb + 2) * IST + r] = v.z;
    IsT[(kb + 3) * IST + r] = v.w;
  }
  __syncthreads();
  int dgrp = tid & 15;
  int rq = tid >> 4;
  float4 acc0 = {0.f, 0.f, 0.f, 0.f}, acc1 = acc0, acc2 = acc0, acc3 = acc0;
  for (int k = 0; k < 64; ++k) {
    float4 wv = *(const float4*)(&Ws[k * 64 + dgrp * 4]);
    float4 iv = *(const float4*)(&IsT[k * IST + rq * 4]);
    acc0.x += iv.x * wv.x; acc0.y += iv.x * wv.y; acc0.z += iv.x * wv.z; acc0.w += iv.x * wv.w;
    acc1.x += iv.y * wv.x; acc1.y += iv.y * wv.y; acc1.z += iv.y * wv.z; acc1.w += iv.y * wv.w;
    acc2.x += iv.z * wv.x; acc2.y += iv.z * wv.y; acc2.z += iv.z * wv.z; acc2.w += iv.z * wv.w;
    acc3.x += iv.w * wv.x; acc3.y += iv.w * wv.y; acc3.z += iv.w * wv.z; acc3.w += iv.w * wv.w;
  }
  int rbase = row0 + rq * 4;
  if (rbase + 0 < n) *(float4*)(&out[(size_t)(rbase + 0) * 64 + dgrp * 4]) = acc0;
  if (rbase + 1 < n) *(float4*)(&out[(size_t)(rbase + 1) * 64 + dgrp * 4]) = acc1;
  if (rbase + 2 < n) *(float4*)(&out[(size_t)(rbase + 2) * 64 + dgrp * 4]) = acc2;
  if (rbase + 3 < n) *(float4*)(&out[(size_t)(rbase + 3) * 64 + dgrp * 4]) = acc3;
}

// ---------------- gather: 2 nodes per wave (half-wave float2 lanes) -------------
// o[c] = b + dinv[c]^2*h[c] + dinv[c] * sum_j dinv[r_j]*h[r_j]
__global__ __launch_bounds__(256) void k_gather(const int* __restrict__ starts,
                                                const int* __restrict__ srcs,
                                                const float* __restrict__ dinv,
                                                const float* __restrict__ h,
                                                const float* __restrict__ bias,
                                                float* __restrict__ o, int n) {
  int node = blockIdx.x * 8 + (threadIdx.x >> 5);
  if (node >= n) return;
  int l2 = (threadIdx.x & 31) * 2;  // feature pair index
  int s = starts[node];
  int e1 = starts[node + 1];
  int deg = e1 - s;
  float dc = dinv[node];
  float2 hs = *(const float2*)(&h[(size_t)node * 64 + l2]);
  float2 bv = *(const float2*)(&bias[l2]);
  float ax = 0.f, ay = 0.f;  // edge accumulator (pre-dc)
  int j = 0;
  for (; j + 3 < deg; j += 4) {
    int r0 = srcs[s + j + 0];
    int r1 = srcs[s + j + 1];
    int r2 = srcs[s + j + 2];
    int r3 = srcs[s + j + 3];
    float w0 = dinv[r0], w1 = dinv[r1], w2 = dinv[r2], w3 = dinv[r3];
    float2 v0 = *(const float2*)(&h[(size_t)r0 * 64 + l2]);
    float2 v1 = *(const float2*)(&h[(size_t)r1 * 64 + l2]);
    float2 v2 = *(const float2*)(&h[(size_t)r2 * 64 + l2]);
    float2 v3 = *(const float2*)(&h[(size_t)r3 * 64 + l2]);
    ax += w0 * v0.x + w1 * v1.x + w2 * v2.x + w3 * v3.x;
    ay += w0 * v0.y + w1 * v1.y + w2 * v2.y + w3 * v3.y;
  }
  for (; j < deg; ++j) {
    int r = srcs[s + j];
    float w = dinv[r];
    float2 v = *(const float2*)(&h[(size_t)r * 64 + l2]);
    ax += w * v.x;
    ay += w * v.y;
  }
  float2 res;
  res.x = bv.x + dc * dc * hs.x + dc * ax;
  res.y = bv.y + dc * dc * hs.y + dc * ay;
  *(float2*)(&o[(size_t)node * 64 + l2]) = res;
}

// ---------------- pooling: batch sorted; 1 wave per 64-node chunk ----------------
__global__ void k_pool(const float* __restrict__ o, const int* __restrict__ batch,
                       float* __restrict__ sums, float* __restrict__ cntf, int n) {
  int d = threadIdx.x;
  int start = blockIdx.x * 64;
  if (start >= n) return;
  int end = min(start + 64, n);
  int curg = batch[start];
  float acc = 0.f, cnt = 0.f;
  for (int i = start; i < end; ++i) {
    int g = batch[i];
    if (g != curg) {
      unsafeAtomicAdd(&sums[curg * 64 + d], acc);
      if (d == 0) unsafeAtomicAdd(&cntf[curg], cnt);
      acc = 0.f;
      cnt = 0.f;
      curg = g;
    }
    acc += o[(size_t)i * 64 + d];
    cnt += 1.f;
  }
  unsafeAtomicAdd(&sums[curg * 64 + d], acc);
  if (d == 0) unsafeAtomicAdd(&cntf[curg], cnt);
}

// ---------------- final ----------------
__global__ void k_final(const float* __restrict__ sums, const float* __restrict__ cntf,
                        float* __restrict__ out) {
  int i = blockIdx.x * 256 + threadIdx.x;
  if (i < NG * DFEAT) out[i] = sums[i] / fmaxf(cntf[i >> 6], 1.0f);
}

extern "C" void kernel_launch(void* const* d_in, const int* in_sizes, int n_in,
                              void* d_out, int out_size, void* d_ws, size_t ws_size,
                              hipStream_t stream) {
  const float* x = (const float*)d_in[0];
  const int* ei = (const int*)d_in[1];
  const int* bat = (const int*)d_in[2];
  const float* W1 = (const float*)d_in[3];
  const float* b1 = (const float*)d_in[4];
  const float* W2 = (const float*)d_in[5];
  const float* b2 = (const float*)d_in[6];
  float* out = (float*)d_out;

  int n = in_sizes[0] / 64;  // 100000
  int e = in_sizes[1] / 2;   // 1000000
  const int* rowp = ei;      // sources
  const int* colp = ei + e;  // targets
  int nb = (n + TILE - 1) / TILE;  // 782 tiles

  // workspace: [gcount nb][sums][cntf] (zeroed) | base, cursor, dinv, starts,
  // srcs, bufA (pairs aliases bufA's first 8 MB), bufB.  Total ~56 MB.
  char* ws = (char*)d_ws;
  size_t off = 0;
  auto alloc = [&](size_t elems) {
    void* p = ws + off;
    off += ((elems * 4 + 255) & ~(size_t)255);
    return p;
  };
  int* gcount = (int*)alloc(nb);
  float* sums = (float*)alloc(NG * DFEAT);
  float* cntf = (float*)alloc(NG);
  size_t zbytes = off;
  int* base = (int*)alloc(nb + 1);
  int* cursor = (int*)alloc(nb);
  float* dinv = (float*)alloc(n);
  int* starts = (int*)alloc(n + 1);
  int* srcs = (int*)alloc(e);
  float* bufA = (float*)alloc((size_t)n * 64);
  float* bufB = (float*)alloc((size_t)n * 64);
  int2* pairs = (int2*)bufA;  // dead after k_csr; bufA written only after that

  int nbe = (e + 255) / 256;
  int nbg = (n + 63) / 64;
  int nbw = (n + 7) / 8;  // gather blocks: 8 nodes each (2 per wave)

  hipMemsetAsync(gcount, 0, zbytes, stream);
  k_hist<<<256, 256, nb * sizeof(int), stream>>>(colp, gcount, e, nb, 256);
  k_bscan<<<1, 1024, 0, stream>>>(gcount, base, cursor, nb);
  k_bin<<<nbe, 256, 0, stream>>>(rowp, colp, cursor, pairs, e);
  k_csr<<<nb, 256, 0, stream>>>(pairs, base, starts, srcs, dinv, n, e);

  // layer 1: gemm(x,W1) -> bufA ; gather(bufA) -> bufB
  k_gemm<<<nbg, 256, 0, stream>>>(x, W1, bufA, n);
  k_gather<<<nbw, 256, 0, stream>>>(starts, srcs, dinv, bufA, b1, bufB, n);

  // layer 2: gemm(bufB,W2) -> bufA ; gather(bufA) -> bufB
  k_gemm<<<nbg, 256, 0, stream>>>(bufB, W2, bufA, n);
  k_gather<<<nbw, 256, 0, stream>>>(starts, srcs, dinv, bufA, b2, bufB, n);

  // pool on bufB
  k_pool<<<(n + 63) / 64, 64, 0, stream>>>(bufB, bat, sums, cntf, n);
  k_final<<<(NG * DFEAT + 255) / 256, 256, 0, stream>>>(sums, cntf, out);
}

// Round 6
// 267.652 us; speedup vs baseline: 4.7358x; 1.8366x over previous
//
#include <hip/hip_runtime.h>

#define DFEAT 64
#define NG 64
#define TILE 128        // nodes per bucket/tile (bucket = tgt >> 7)
#define NBLK 256        // binning blocks (must equal blockDim of k_colscan)
#define NBMAX 1024      // max buckets supported in LDS

// ---------------- pass A: per-block-chunk bucket histogram -> cnt_m[blk][b] -----
__global__ __launch_bounds__(256) void k_cnt(const int* __restrict__ col,
                                             int* __restrict__ cnt_m,
                                             int e, int nb, int chunk) {
  __shared__ int hist[NBMAX];
  int tid = threadIdx.x;
  int blk = blockIdx.x;
  for (int b = tid; b < nb; b += 256) hist[b] = 0;
  __syncthreads();
  int lo = blk * chunk, hi = min(lo + chunk, e);
  for (int i = lo + tid; i < hi; i += 256)
    atomicAdd(&hist[col[i] >> 7], 1);
  __syncthreads();
  for (int b = tid; b < nb; b += 256)
    cnt_m[(size_t)blk * nb + b] = hist[b];
}

// ---------------- pass B: per-bucket scan over blocks (in place) + totals -------
__global__ __launch_bounds__(256) void k_colscan(int* __restrict__ cnt_m,
                                                 int* __restrict__ gcount, int nb) {
  __shared__ int sh[256];
  int tid = threadIdx.x;
  int b = blockIdx.x;
  int v = cnt_m[(size_t)tid * nb + b];
  sh[tid] = v;
  __syncthreads();
  for (int off = 1; off < 256; off <<= 1) {
    int t = (tid >= off) ? sh[tid - off] : 0;
    __syncthreads();
    sh[tid] += t;
    __syncthreads();
  }
  cnt_m[(size_t)tid * nb + b] = sh[tid] - v;  // exclusive over blocks
  if (tid == 255) gcount[b] = sh[255];
}

// ---------------- scan bucket totals -> base[0..nb] ----------------------------
__global__ __launch_bounds__(1024) void k_bscan(const int* __restrict__ gcount,
                                                int* __restrict__ base, int nb) {
  __shared__ int sh[1024];
  int tid = threadIdx.x;
  int v = (tid < nb) ? gcount[tid] : 0;
  sh[tid] = v;
  __syncthreads();
  for (int off = 1; off < 1024; off <<= 1) {
    int t = (tid >= off) ? sh[tid - off] : 0;
    __syncthreads();
    sh[tid] += t;
    __syncthreads();
  }
  if (tid < nb) base[tid] = sh[tid] - v;
  if (tid == 0) base[nb] = sh[1023];
}

// ---------------- pass C: place edges, LDS cursors only, packed payload --------
// pairs[pos] = src | ((tgt & 127) << 20)   (requires n < 2^20)
__global__ __launch_bounds__(256) void k_bin2(const int* __restrict__ row,
                                              const int* __restrict__ col,
                                              const int* __restrict__ base,
                                              const int* __restrict__ cnt_m,
                                              int* __restrict__ pairs,
                                              int e, int nb, int chunk) {
  __shared__ int gl[NBMAX];
  __shared__ int lcur[NBMAX];
  int tid = threadIdx.x;
  int blk = blockIdx.x;
  for (int b = tid; b < nb; b += 256) {
    gl[b] = base[b] + cnt_m[(size_t)blk * nb + b];
    lcur[b] = 0;
  }
  __syncthreads();
  int lo = blk * chunk, hi = min(lo + chunk, e);
  for (int i = lo + tid; i < hi; i += 256) {
    int s = row[i], t = col[i];
    int b = t >> 7;
    int pos = gl[b] + atomicAdd(&lcur[b], 1);
    pairs[pos] = s | ((t & (TILE - 1)) << 20);
  }
}

// ---------------- per-tile CSR: node-ordered srcs, starts[], dinv ---------------
__global__ __launch_bounds__(256) void k_csr(const int* __restrict__ pairs,
                                             const int* __restrict__ base,
                                             int* __restrict__ starts,
                                             int* __restrict__ srcs,
                                             float* __restrict__ dinv,
                                             int n, int e) {
  __shared__ int cnt[TILE];
  __shared__ int cur[TILE];
  __shared__ int sc[TILE];
  int tid = threadIdx.x;
  int b = blockIdx.x;
  int tile0 = b * TILE;
  if (tid < TILE) cnt[tid] = 0;
  __syncthreads();
  int e0 = base[b], e1 = base[b + 1];
  for (int i = e0 + tid; i < e1; i += 256)
    atomicAdd(&cnt[(unsigned)pairs[i] >> 20], 1);
  __syncthreads();
  int c = (tid < TILE) ? cnt[tid] : 0;
  if (tid < TILE) sc[tid] = c;
  __syncthreads();
  for (int off = 1; off < TILE; off <<= 1) {
    int t = (tid < TILE && tid >= off) ? sc[tid - off] : 0;
    __syncthreads();
    if (tid < TILE) sc[tid] += t;
    __syncthreads();
  }
  if (tid < TILE) {
    int excl = sc[tid] - c;
    cur[tid] = excl;
    int node = tile0 + tid;
    if (node < n) {
      starts[node] = e0 + excl;
      dinv[node] = rsqrtf(1.0f + (float)c);
    }
  }
  if (b == 0 && tid == 0) starts[n] = e;
  __syncthreads();
  for (int i = e0 + tid; i < e1; i += 256) {
    int p = pairs[i];
    int pos = atomicAdd(&cur[(unsigned)p >> 20], 1);
    srcs[e0 + pos] = p & 0xFFFFF;
  }
}

// ---------------- GEMM: out[n,64] = in[n,64] @ W[64,64] ----------------
#define IST 68
__global__ __launch_bounds__(256) void k_gemm(const float* __restrict__ in,
                                              const float* __restrict__ W,
                                              float* __restrict__ out, int n) {
  __shared__ float Ws[64 * 64];
  __shared__ float IsT[64 * IST];
  int tid = threadIdx.x;
  int row0 = blockIdx.x * 64;
  for (int j = tid; j < 4096; j += 256) Ws[j] = W[j];
  for (int s = 0; s < 4; ++s) {
    int g = tid * 4 + s * 1024;
    int r = g >> 6;
    int kb = g & 63;
    float4 v = make_float4(0.f, 0.f, 0.f, 0.f);
    if (row0 + r < n) v = *(const float4*)(&in[(size_t)(row0 + r) * 64 + kb]);
    IsT[(kb + 0) * IST + r] = v.x;
    IsT[(kb + 1) * IST + r] = v.y;
    IsT[(kb + 2) * IST + r] = v.z;
    IsT[(kb + 3) * IST + r] = v.w;
  }
  __syncthreads();
  int dgrp = tid & 15;
  int rq = tid >> 4;
  float4 acc0 = {0.f, 0.f, 0.f, 0.f}, acc1 = acc0, acc2 = acc0, acc3 = acc0;
  for (int k = 0; k < 64; ++k) {
    float4 wv = *(const float4*)(&Ws[k * 64 + dgrp * 4]);
    float4 iv = *(const float4*)(&IsT[k * IST + rq * 4]);
    acc0.x += iv.x * wv.x; acc0.y += iv.x * wv.y; acc0.z += iv.x * wv.z; acc0.w += iv.x * wv.w;
    acc1.x += iv.y * wv.x; acc1.y += iv.y * wv.y; acc1.z += iv.y * wv.z; acc1.w += iv.y * wv.w;
    acc2.x += iv.z * wv.x; acc2.y += iv.z * wv.y; acc2.z += iv.z * wv.z; acc2.w += iv.z * wv.w;
    acc3.x += iv.w * wv.x; acc3.y += iv.w * wv.y; acc3.z += iv.w * wv.z; acc3.w += iv.w * wv.w;
  }
  int rbase = row0 + rq * 4;
  if (rbase + 0 < n) *(float4*)(&out[(size_t)(rbase + 0) * 64 + dgrp * 4]) = acc0;
  if (rbase + 1 < n) *(float4*)(&out[(size_t)(rbase + 1) * 64 + dgrp * 4]) = acc1;
  if (rbase + 2 < n) *(float4*)(&out[(size_t)(rbase + 2) * 64 + dgrp * 4]) = acc2;
  if (rbase + 3 < n) *(float4*)(&out[(size_t)(rbase + 3) * 64 + dgrp * 4]) = acc3;
}

// ---------------- gather: 2 nodes per wave (half-wave float2 lanes) -------------
__global__ __launch_bounds__(256) void k_gather(const int* __restrict__ starts,
                                                const int* __restrict__ srcs,
                                                const float* __restrict__ dinv,
                                                const float* __restrict__ h,
                                                const float* __restrict__ bias,
                                                float* __restrict__ o, int n) {
  int node = blockIdx.x * 8 + (threadIdx.x >> 5);
  if (node >= n) return;
  int l2 = (threadIdx.x & 31) * 2;
  int s = starts[node];
  int e1 = starts[node + 1];
  int deg = e1 - s;
  float dc = dinv[node];
  float2 hs = *(const float2*)(&h[(size_t)node * 64 + l2]);
  float2 bv = *(const float2*)(&bias[l2]);
  float ax = 0.f, ay = 0.f;
  int j = 0;
  for (; j + 3 < deg; j += 4) {
    int r0 = srcs[s + j + 0];
    int r1 = srcs[s + j + 1];
    int r2 = srcs[s + j + 2];
    int r3 = srcs[s + j + 3];
    float w0 = dinv[r0], w1 = dinv[r1], w2 = dinv[r2], w3 = dinv[r3];
    float2 v0 = *(const float2*)(&h[(size_t)r0 * 64 + l2]);
    float2 v1 = *(const float2*)(&h[(size_t)r1 * 64 + l2]);
    float2 v2 = *(const float2*)(&h[(size_t)r2 * 64 + l2]);
    float2 v3 = *(const float2*)(&h[(size_t)r3 * 64 + l2]);
    ax += w0 * v0.x + w1 * v1.x + w2 * v2.x + w3 * v3.x;
    ay += w0 * v0.y + w1 * v1.y + w2 * v2.y + w3 * v3.y;
  }
  for (; j < deg; ++j) {
    int r = srcs[s + j];
    float w = dinv[r];
    float2 v = *(const float2*)(&h[(size_t)r * 64 + l2]);
    ax += w * v.x;
    ay += w * v.y;
  }
  float2 res;
  res.x = bv.x + dc * dc * hs.x + dc * ax;
  res.y = bv.y + dc * dc * hs.y + dc * ay;
  *(float2*)(&o[(size_t)node * 64 + l2]) = res;
}

// ---------------- pooling: batch sorted; 1 wave per 64-node chunk ----------------
__global__ void k_pool(const float* __restrict__ o, const int* __restrict__ batch,
                       float* __restrict__ sums, float* __restrict__ cntf, int n) {
  int d = threadIdx.x;
  int start = blockIdx.x * 64;
  if (start >= n) return;
  int end = min(start + 64, n);
  int curg = batch[start];
  float acc = 0.f, cnt = 0.f;
  for (int i = start; i < end; ++i) {
    int g = batch[i];
    if (g != curg) {
      unsafeAtomicAdd(&sums[curg * 64 + d], acc);
      if (d == 0) unsafeAtomicAdd(&cntf[curg], cnt);
      acc = 0.f;
      cnt = 0.f;
      curg = g;
    }
    acc += o[(size_t)i * 64 + d];
    cnt += 1.f;
  }
  unsafeAtomicAdd(&sums[curg * 64 + d], acc);
  if (d == 0) unsafeAtomicAdd(&cntf[curg], cnt);
}

// ---------------- final ----------------
__global__ void k_final(const float* __restrict__ sums, const float* __restrict__ cntf,
                        float* __restrict__ out) {
  int i = blockIdx.x * 256 + threadIdx.x;
  if (i < NG * DFEAT) out[i] = sums[i] / fmaxf(cntf[i >> 6], 1.0f);
}

extern "C" void kernel_launch(void* const* d_in, const int* in_sizes, int n_in,
                              void* d_out, int out_size, void* d_ws, size_t ws_size,
                              hipStream_t stream) {
  const float* x = (const float*)d_in[0];
  const int* ei = (const int*)d_in[1];
  const int* bat = (const int*)d_in[2];
  const float* W1 = (const float*)d_in[3];
  const float* b1 = (const float*)d_in[4];
  const float* W2 = (const float*)d_in[5];
  const float* b2 = (const float*)d_in[6];
  float* out = (float*)d_out;

  int n = in_sizes[0] / 64;  // 100000
  int e = in_sizes[1] / 2;   // 1000000
  const int* rowp = ei;      // sources
  const int* colp = ei + e;  // targets
  int nb = (n + TILE - 1) / TILE;      // 782 buckets (< NBMAX)
  int chunk = (e + NBLK - 1) / NBLK;   // edges per binning block

  // workspace: [sums][cntf] (zeroed) | gcount, base, cnt_m, dinv, starts, srcs,
  // bufA (packed pairs alias bufA), bufB.  Total ~57 MB.
  char* ws = (char*)d_ws;
  size_t off = 0;
  auto alloc = [&](size_t elems) {
    void* p = ws + off;
    off += ((elems * 4 + 255) & ~(size_t)255);
    return p;
  };
  float* sums = (float*)alloc(NG * DFEAT);
  float* cntf = (float*)alloc(NG);
  size_t zbytes = off;
  int* gcount = (int*)alloc(nb);
  int* base = (int*)alloc(nb + 1);
  int* cnt_m = (int*)alloc((size_t)NBLK * nb);
  float* dinv = (float*)alloc(n);
  int* starts = (int*)alloc(n + 1);
  int* srcs = (int*)alloc(e);
  float* bufA = (float*)alloc((size_t)n * 64);
  float* bufB = (float*)alloc((size_t)n * 64);
  int* pairs = (int*)bufA;  // dead after k_csr; bufA first written after that

  int nbg = (n + 63) / 64;
  int nbw = (n + 7) / 8;

  hipMemsetAsync(sums, 0, zbytes, stream);
  k_cnt<<<NBLK, 256, 0, stream>>>(colp, cnt_m, e, nb, chunk);
  k_colscan<<<nb, 256, 0, stream>>>(cnt_m, gcount, nb);
  k_bscan<<<1, 1024, 0, stream>>>(gcount, base, nb);
  k_bin2<<<NBLK, 256, 0, stream>>>(rowp, colp, base, cnt_m, pairs, e, nb, chunk);
  k_csr<<<nb, 256, 0, stream>>>(pairs, base, starts, srcs, dinv, n, e);

  // layer 1: gemm(x,W1) -> bufA ; gather(bufA) -> bufB
  k_gemm<<<nbg, 256, 0, stream>>>(x, W1, bufA, n);
  k_gather<<<nbw, 256, 0, stream>>>(starts, srcs, dinv, bufA, b1, bufB, n);

  // layer 2: gemm(bufB,W2) -> bufA ; gather(bufA) -> bufB
  k_gemm<<<nbg, 256, 0, stream>>>(bufB, W2, bufA, n);
  k_gather<<<nbw, 256, 0, stream>>>(starts, srcs, dinv, bufA, b2, bufB, n);

  // pool on bufB
  k_pool<<<(n + 63) / 64, 64, 0, stream>>>(bufB, bat, sums, cntf, n);
  k_final<<<(NG * DFEAT + 255) / 256, 256, 0, stream>>>(sums, cntf, out);
}

// Round 7
// 254.700 us; speedup vs baseline: 4.9766x; 1.0509x over previous
//
#include <hip/hip_runtime.h>

#define DFEAT 64
#define NG 64
#define TILE 128        // nodes per bucket/tile (bucket = tgt >> 7)
#define NBLK 256        // binning blocks (must equal blockDim of k_colscan)
#define NBMAX 1024      // max buckets supported in LDS

// ---------------- pass A: per-block-chunk bucket histogram -> cnt_m[blk][b] -----
__global__ __launch_bounds__(256) void k_cnt(const int* __restrict__ col,
                                             int* __restrict__ cnt_m,
                                             int e, int nb, int chunk) {
  __shared__ int hist[NBMAX];
  int tid = threadIdx.x;
  int blk = blockIdx.x;
  for (int b = tid; b < nb; b += 256) hist[b] = 0;
  __syncthreads();
  int lo = blk * chunk, hi = min(lo + chunk, e);
  for (int i = lo + tid; i < hi; i += 256)
    atomicAdd(&hist[col[i] >> 7], 1);
  __syncthreads();
  for (int b = tid; b < nb; b += 256)
    cnt_m[(size_t)blk * nb + b] = hist[b];
}

// ---------------- pass B: per-bucket scan over blocks (in place) + totals -------
__global__ __launch_bounds__(256) void k_colscan(int* __restrict__ cnt_m,
                                                 int* __restrict__ gcount, int nb) {
  __shared__ int sh[256];
  int tid = threadIdx.x;
  int b = blockIdx.x;
  int v = cnt_m[(size_t)tid * nb + b];
  sh[tid] = v;
  __syncthreads();
  for (int off = 1; off < 256; off <<= 1) {
    int t = (tid >= off) ? sh[tid - off] : 0;
    __syncthreads();
    sh[tid] += t;
    __syncthreads();
  }
  cnt_m[(size_t)tid * nb + b] = sh[tid] - v;  // exclusive over blocks
  if (tid == 255) gcount[b] = sh[255];
}

// ---------------- scan bucket totals -> base[0..nb] ----------------------------
__global__ __launch_bounds__(1024) void k_bscan(const int* __restrict__ gcount,
                                                int* __restrict__ base, int nb) {
  __shared__ int sh[1024];
  int tid = threadIdx.x;
  int v = (tid < nb) ? gcount[tid] : 0;
  sh[tid] = v;
  __syncthreads();
  for (int off = 1; off < 1024; off <<= 1) {
    int t = (tid >= off) ? sh[tid - off] : 0;
    __syncthreads();
    sh[tid] += t;
    __syncthreads();
  }
  if (tid < nb) base[tid] = sh[tid] - v;
  if (tid == 0) base[nb] = sh[1023];
}

// ---------------- pass C: place edges, LDS cursors only, packed payload --------
// pairs[pos] = src | ((tgt & 127) << 20)   (requires n < 2^20)
__global__ __launch_bounds__(256) void k_bin2(const int* __restrict__ row,
                                              const int* __restrict__ col,
                                              const int* __restrict__ base,
                                              const int* __restrict__ cnt_m,
                                              int* __restrict__ pairs,
                                              int e, int nb, int chunk) {
  __shared__ int gl[NBMAX];
  __shared__ int lcur[NBMAX];
  int tid = threadIdx.x;
  int blk = blockIdx.x;
  for (int b = tid; b < nb; b += 256) {
    gl[b] = base[b] + cnt_m[(size_t)blk * nb + b];
    lcur[b] = 0;
  }
  __syncthreads();
  int lo = blk * chunk, hi = min(lo + chunk, e);
  for (int i = lo + tid; i < hi; i += 256) {
    int s = row[i], t = col[i];
    int b = t >> 7;
    int pos = gl[b] + atomicAdd(&lcur[b], 1);
    pairs[pos] = s | ((t & (TILE - 1)) << 20);
  }
}

// ---------------- per-tile CSR: node-ordered srcs, starts[], dinv ---------------
__global__ __launch_bounds__(256) void k_csr(const int* __restrict__ pairs,
                                             const int* __restrict__ base,
                                             int* __restrict__ starts,
                                             int* __restrict__ srcs,
                                             float* __restrict__ dinv,
                                             int n, int e) {
  __shared__ int cnt[TILE];
  __shared__ int cur[TILE];
  __shared__ int sc[TILE];
  int tid = threadIdx.x;
  int b = blockIdx.x;
  int tile0 = b * TILE;
  if (tid < TILE) cnt[tid] = 0;
  __syncthreads();
  int e0 = base[b], e1 = base[b + 1];
  for (int i = e0 + tid; i < e1; i += 256)
    atomicAdd(&cnt[(unsigned)pairs[i] >> 20], 1);
  __syncthreads();
  int c = (tid < TILE) ? cnt[tid] : 0;
  if (tid < TILE) sc[tid] = c;
  __syncthreads();
  for (int off = 1; off < TILE; off <<= 1) {
    int t = (tid < TILE && tid >= off) ? sc[tid - off] : 0;
    __syncthreads();
    if (tid < TILE) sc[tid] += t;
    __syncthreads();
  }
  if (tid < TILE) {
    int excl = sc[tid] - c;
    cur[tid] = excl;
    int node = tile0 + tid;
    if (node < n) {
      starts[node] = e0 + excl;
      dinv[node] = rsqrtf(1.0f + (float)c);
    }
  }
  if (b == 0 && tid == 0) starts[n] = e;
  __syncthreads();
  for (int i = e0 + tid; i < e1; i += 256) {
    int p = pairs[i];
    int pos = atomicAdd(&cur[(unsigned)p >> 20], 1);
    srcs[e0 + pos] = p & 0xFFFFF;
  }
}

// ---------------- u = A_hat * 1 : u[c] = dinv[c]*(dinv[c] + sum dinv[src]) ------
__global__ void k_u(const int* __restrict__ starts, const int* __restrict__ srcs,
                    const float* __restrict__ dinv, float* __restrict__ u, int n) {
  int i = blockIdx.x * 256 + threadIdx.x;
  if (i >= n) return;
  int s = starts[i], e1 = starts[i + 1];
  float d = dinv[i];
  float acc = d;
  for (int j = s; j < e1; ++j) acc += dinv[srcs[j]];
  u[i] = d * acc;
}

// ---------------- WW = W1@W2 (64x64), bw = b1^T @ W2 ----------------------------
__global__ __launch_bounds__(256) void k_w12(const float* __restrict__ W1,
                                             const float* __restrict__ W2,
                                             const float* __restrict__ b1,
                                             float* __restrict__ WW,
                                             float* __restrict__ bw) {
  __shared__ float w1[4096], w2[4096];
  int tid = threadIdx.x;
  for (int i = tid; i < 4096; i += 256) { w1[i] = W1[i]; w2[i] = W2[i]; }
  __syncthreads();
  for (int p = tid; p < 4096; p += 256) {
    int k = p >> 6, d = p & 63;
    float a = 0.f;
    for (int m = 0; m < 64; ++m) a += w1[k * 64 + m] * w2[m * 64 + d];
    WW[p] = a;
  }
  if (tid < 64) {
    float a = 0.f;
    for (int k = 0; k < 64; ++k) a += b1[k] * w2[k * 64 + tid];
    bw[tid] = a;
  }
}

// ---------------- gather: o = A_hat * h  (2 nodes per wave, float2 lanes) -------
__global__ __launch_bounds__(256) void k_gather(const int* __restrict__ starts,
                                                const int* __restrict__ srcs,
                                                const float* __restrict__ dinv,
                                                const float* __restrict__ h,
                                                float* __restrict__ o, int n) {
  int node = blockIdx.x * 8 + (threadIdx.x >> 5);
  if (node >= n) return;
  int l2 = (threadIdx.x & 31) * 2;
  int s = starts[node];
  int e1 = starts[node + 1];
  int deg = e1 - s;
  float dc = dinv[node];
  float2 hs = *(const float2*)(&h[(size_t)node * 64 + l2]);
  float ax = 0.f, ay = 0.f;
  int j = 0;
  for (; j + 3 < deg; j += 4) {
    int r0 = srcs[s + j + 0];
    int r1 = srcs[s + j + 1];
    int r2 = srcs[s + j + 2];
    int r3 = srcs[s + j + 3];
    float w0 = dinv[r0], w1 = dinv[r1], w2 = dinv[r2], w3 = dinv[r3];
    float2 v0 = *(const float2*)(&h[(size_t)r0 * 64 + l2]);
    float2 v1 = *(const float2*)(&h[(size_t)r1 * 64 + l2]);
    float2 v2 = *(const float2*)(&h[(size_t)r2 * 64 + l2]);
    float2 v3 = *(const float2*)(&h[(size_t)r3 * 64 + l2]);
    ax += w0 * v0.x + w1 * v1.x + w2 * v2.x + w3 * v3.x;
    ay += w0 * v0.y + w1 * v1.y + w2 * v2.y + w3 * v3.y;
  }
  for (; j < deg; ++j) {
    int r = srcs[s + j];
    float w = dinv[r];
    float2 v = *(const float2*)(&h[(size_t)r * 64 + l2]);
    ax += w * v.x;
    ay += w * v.y;
  }
  float2 res;
  res.x = dc * dc * hs.x + dc * ax;
  res.y = dc * dc * hs.y + dc * ay;
  *(float2*)(&o[(size_t)node * 64 + l2]) = res;
}

// ---------------- pool z2 rows, u, and counts (batch sorted) --------------------
__global__ void k_pool2(const float* __restrict__ z2, const float* __restrict__ u,
                        const int* __restrict__ batch, float* __restrict__ S,
                        float* __restrict__ T, float* __restrict__ cntf, int n) {
  int d = threadIdx.x;
  int start = blockIdx.x * 64;
  if (start >= n) return;
  int end = min(start + 64, n);
  int curg = batch[start];
  float acc = 0.f, cnt = 0.f, ua = 0.f;
  for (int i = start; i < end; ++i) {
    int g = batch[i];
    if (g != curg) {
      unsafeAtomicAdd(&S[curg * 64 + d], acc);
      if (d == 0) {
        unsafeAtomicAdd(&cntf[curg], cnt);
        unsafeAtomicAdd(&T[curg], ua);
      }
      acc = 0.f; cnt = 0.f; ua = 0.f;
      curg = g;
    }
    acc += z2[(size_t)i * 64 + d];
    if (d == 0) { cnt += 1.f; ua += u[i]; }
  }
  unsafeAtomicAdd(&S[curg * 64 + d], acc);
  if (d == 0) {
    unsafeAtomicAdd(&cntf[curg], cnt);
    unsafeAtomicAdd(&T[curg], ua);
  }
}

// ---------------- final: out[g] = (S[g]@WW + T[g]*bw)/cnt + b2 ------------------
__global__ __launch_bounds__(256) void k_final2(const float* __restrict__ S,
                                                const float* __restrict__ T,
                                                const float* __restrict__ cntf,
                                                const float* __restrict__ WW,
                                                const float* __restrict__ bw,
                                                const float* __restrict__ b2,
                                                float* __restrict__ out) {
  __shared__ float sS[4096], sW[4096];
  int tid = threadIdx.x;
  for (int i = tid; i < 4096; i += 256) { sS[i] = S[i]; sW[i] = WW[i]; }
  __syncthreads();
  for (int p = tid; p < 4096; p += 256) {
    int g = p >> 6, d = p & 63;
    float a = 0.f;
    for (int k = 0; k < 64; ++k) a += sS[g * 64 + k] * sW[k * 64 + d];
    float c = fmaxf(cntf[g], 1.0f);
    out[p] = (a + T[g] * bw[d]) / c + b2[d];
  }
}

extern "C" void kernel_launch(void* const* d_in, const int* in_sizes, int n_in,
                              void* d_out, int out_size, void* d_ws, size_t ws_size,
                              hipStream_t stream) {
  const float* x = (const float*)d_in[0];
  const int* ei = (const int*)d_in[1];
  const int* bat = (const int*)d_in[2];
  const float* W1 = (const float*)d_in[3];
  const float* b1 = (const float*)d_in[4];
  const float* W2 = (const float*)d_in[5];
  const float* b2 = (const float*)d_in[6];
  float* out = (float*)d_out;

  int n = in_sizes[0] / 64;  // 100000
  int e = in_sizes[1] / 2;   // 1000000
  const int* rowp = ei;      // sources
  const int* colp = ei + e;  // targets
  int nb = (n + TILE - 1) / TILE;      // 782 buckets (< NBMAX)
  int chunk = (e + NBLK - 1) / NBLK;   // edges per binning block

  // workspace: [S][cntf][T] (zeroed) | gcount, base, cnt_m, dinv, starts, srcs,
  // u, WW, bw, z1 (packed pairs alias z1), z2.  Total ~57 MB.
  char* ws = (char*)d_ws;
  size_t off = 0;
  auto alloc = [&](size_t elems) {
    void* p = ws + off;
    off += ((elems * 4 + 255) & ~(size_t)255);
    return p;
  };
  float* S = (float*)alloc(NG * DFEAT);
  float* cntf = (float*)alloc(NG);
  float* T = (float*)alloc(NG);
  size_t zbytes = off;
  int* gcount = (int*)alloc(nb);
  int* base = (int*)alloc(nb + 1);
  int* cnt_m = (int*)alloc((size_t)NBLK * nb);
  float* dinv = (float*)alloc(n);
  int* starts = (int*)alloc(n + 1);
  int* srcs = (int*)alloc(e);
  float* u = (float*)alloc(n);
  float* WW = (float*)alloc(DFEAT * DFEAT);
  float* bw = (float*)alloc(DFEAT);
  float* z1 = (float*)alloc((size_t)n * 64);
  float* z2 = (float*)alloc((size_t)n * 64);
  int* pairs = (int*)z1;  // dead after k_csr; z1 first written after that

  int nbn = (n + 255) / 256;
  int nbw = (n + 7) / 8;

  hipMemsetAsync(S, 0, zbytes, stream);
  k_cnt<<<NBLK, 256, 0, stream>>>(colp, cnt_m, e, nb, chunk);
  k_colscan<<<nb, 256, 0, stream>>>(cnt_m, gcount, nb);
  k_bscan<<<1, 1024, 0, stream>>>(gcount, base, nb);
  k_bin2<<<NBLK, 256, 0, stream>>>(rowp, colp, base, cnt_m, pairs, e, nb, chunk);
  k_csr<<<nb, 256, 0, stream>>>(pairs, base, starts, srcs, dinv, n, e);
  k_u<<<nbn, 256, 0, stream>>>(starts, srcs, dinv, u, n);
  k_w12<<<1, 256, 0, stream>>>(W1, W2, b1, WW, bw);

  // z1 = A_hat * x ; z2 = A_hat * z1
  k_gather<<<nbw, 256, 0, stream>>>(starts, srcs, dinv, x, z1, n);
  k_gather<<<nbw, 256, 0, stream>>>(starts, srcs, dinv, z1, z2, n);

  // pool + tiny final matmul
  k_pool2<<<(n + 63) / 64, 64, 0, stream>>>(z2, u, bat, S, T, cntf, n);
  k_final2<<<1, 256, 0, stream>>>(S, T, cntf, WW, bw, b2, out);
}